// Round 4
// baseline (502.579 us; speedup 1.0000x reference)
//
#include <hip/hip_runtime.h>
#include <hip/hip_bf16.h>

// Problem constants
#define NB   256
#define NC   4096
#define NF   64
#define NG   512
#define NH   128
#define NELEM (NB*NC)            // 1048576
#define NSEG  (NB*NG + 1)        // 131073
#define LDX  66                  // row stride of x_with_meta in floats
#define NEGV (-1000000000.0f)
#define TILES 4                  // 128-row tiles per block
#define TILE_ROWS 128
#define GRID_MLP (NELEM/(TILES*TILE_ROWS))   // 2048

typedef __attribute__((ext_vector_type(8))) short short8;
typedef __attribute__((ext_vector_type(4))) float f32x4;

// truncating f32->bf16 pair pack (threshold 2e7 makes RNE unnecessary)
__device__ __forceinline__ unsigned pack2(float x, float y) {
    return (__float_as_uint(y) & 0xFFFF0000u) | (__float_as_uint(x) >> 16);
}
__device__ __forceinline__ unsigned short f2bf(float f) {   // RNE, off hot path
    unsigned u = __float_as_uint(f);
    return (unsigned short)((u + 0x7FFFu + ((u >> 16) & 1u)) >> 16);
}
__device__ __forceinline__ unsigned encf(float f) {
    unsigned u = __float_as_uint(f);
    return (u & 0x80000000u) ? ~u : (u | 0x80000000u);
}
__device__ __forceinline__ float decf(unsigned u) {
    unsigned v = (u & 0x80000000u) ? (u ^ 0x80000000u) : ~u;
    return __uint_as_float(v);
}

// ---- kernel 0: weight prep (RNE, off hot path) ------------------------------
// W0T: [h=128][f=64] bf16 linear (A-frag source for swapped GEMM1)
// W1Ts: [j=128][16 units of 8 bf16], unit index XOR-swizzled: u' = u ^ (j&7)
__global__ void k_prep(const float* __restrict__ W0, const float* __restrict__ W1,
                       unsigned short* __restrict__ W0T, unsigned short* __restrict__ W1Ts) {
    int i = blockIdx.x * 256 + threadIdx.x;
    if (i < 8192) {                       // W0T[j][k] = W0[k][j]
        int j = i >> 6, k = i & 63;
        W0T[i] = f2bf(W0[k * NH + j]);
    } else if (i < 8192 + 16384) {        // W1Ts swizzled: elem (j, c)
        int i2 = i - 8192;
        int j = i2 >> 7, c = i2 & 127;
        int u = c >> 3, d = c & 7;
        W1Ts[(j * 16 + (u ^ (j & 7))) * 8 + d] = f2bf(W1[c * NH + j]);
    }
}

// ---- kernel 1: fused MLP + segment atomics ---------------------------------
// 4 waves x 32 rows = 128-row tiles, TILES per block, barrier-free main loop.
// LDS 52.7KB -> 3 blocks/CU (12 waves).
__global__ __launch_bounds__(256, 3) void k_mlp(
        const float* __restrict__ X,
        const unsigned short* __restrict__ W0T,
        const unsigned short* __restrict__ W1Ts,
        const float* __restrict__ b0, const float* __restrict__ b1,
        const float* __restrict__ W2, const float* __restrict__ b2p,
        float* __restrict__ rawOut, unsigned* __restrict__ mcodeOut,
        unsigned* __restrict__ segCnt, float* __restrict__ segSum,
        unsigned* __restrict__ segMax) {
    __shared__ __align__(16) unsigned short sWs1[16384];     // 32 KB W1 frags (swizzled)
    __shared__ __align__(16) unsigned short sBuf[4][2304];   // 4.5 KB/wave: feats/Hs-half aliased
    __shared__ float sB0[128];
    __shared__ unsigned sMeta[4][2][32];                     // per-wave meta codes, dbuf

    const int t = threadIdx.x, w = t >> 6, l = t & 63;
    const int l15 = l & 15, g = l >> 4;
    const int rx = l15 & 7;

    // stage W1 (pre-swizzled, linear copy; once per block)
    {
        const uint4* src = (const uint4*)W1Ts;
        uint4* dst = (uint4*)sWs1;
#pragma unroll
        for (int i = 0; i < 8; ++i) dst[i * 256 + t] = src[i * 256 + t];
    }
    if (t < 128) sB0[t] = b0[t];

    // loop-invariant register fragments
    short8 w0f[8][2];
#pragma unroll
    for (int n = 0; n < 8; ++n)
#pragma unroll
        for (int kk = 0; kk < 2; ++kk)
            w0f[n][kk] = *(const short8*)(W0T + (n * 16 + l15) * 64 + kk * 32 + g * 8);
    float b1v[8], w2v[8];
#pragma unroll
    for (int n = 0; n < 8; ++n) { b1v[n] = b1[n * 16 + l15]; w2v[n] = W2[n * 16 + l15]; }
    const float b2v = b2p[0];

    __syncthreads();   // only barrier: sWs1/sB0 ready

    unsigned short* buf = sBuf[w];
    const size_t rowwave0 = (size_t)blockIdx.x * (TILES * TILE_ROWS) + w * 32;
    const int sr = l >> 1, sc = l & 1;   // staging role: row sr, col-half sc

    // ---- prologue: stage tile 0 ----
    float2 pf[16];
    unsigned pmc = 0;
    {
        const float* src = X + (rowwave0 + sr) * LDX + sc * 32;
#pragma unroll
        for (int i = 0; i < 16; ++i) pf[i] = *(const float2*)(src + 2 * i);
        if (sc == 1) {
            float2 mt = *(const float2*)(X + (rowwave0 + sr) * LDX + 64);
            pmc = ((unsigned)((int)mt.x + 1) << 1) | (mt.y > 0.f ? 1u : 0u);
        }
    }
    {
        unsigned pk[16];
#pragma unroll
        for (int i = 0; i < 16; ++i) pk[i] = pack2(pf[i].x, pf[i].y);
        unsigned short* d = buf + sr * 72 + sc * 32;
#pragma unroll
        for (int i = 0; i < 4; ++i)
            ((uint4*)d)[i] = make_uint4(pk[4*i], pk[4*i+1], pk[4*i+2], pk[4*i+3]);
        if (sc == 1) sMeta[w][0][sr] = pmc;
    }

    for (int tau = 0; tau < TILES; ++tau) {
        const size_t rowb = rowwave0 + (size_t)tau * TILE_ROWS;

        // 0: issue next tile's global loads (in flight across the iteration)
        if (tau + 1 < TILES) {
            const float* src = X + (rowb + TILE_ROWS + sr) * LDX + sc * 32;
#pragma unroll
            for (int i = 0; i < 16; ++i) pf[i] = *(const float2*)(src + 2 * i);
            if (sc == 1) {
                float2 mt = *(const float2*)(X + (rowb + TILE_ROWS + sr) * LDX + 64);
                pmc = ((unsigned)((int)mt.x + 1) << 1) | (mt.y > 0.f ? 1u : 0u);
            }
        }

        // 1: feats fragments (row rg*16+l15, cols kk*32+g*8..+7)
        short8 bfr[2][2];
#pragma unroll
        for (int rg = 0; rg < 2; ++rg)
#pragma unroll
            for (int kk = 0; kk < 2; ++kk)
                bfr[rg][kk] = *(const short8*)(buf + (rg * 16 + l15) * 72 + kk * 32 + g * 8);

        // 2: GEMM1 (swapped): lane holds h1[row l15][col n*16+g*4+q] per rg
        f32x4 acc[8][2];
#pragma unroll
        for (int n = 0; n < 8; ++n)
#pragma unroll
            for (int rg = 0; rg < 2; ++rg) acc[n][rg] = (f32x4){0.f, 0.f, 0.f, 0.f};
#pragma unroll
        for (int n = 0; n < 8; ++n)
#pragma unroll
            for (int rg = 0; rg < 2; ++rg) {
                acc[n][rg] = __builtin_amdgcn_mfma_f32_16x16x32_bf16(w0f[n][0], bfr[rg][0], acc[n][rg], 0, 0, 0);
                acc[n][rg] = __builtin_amdgcn_mfma_f32_16x16x32_bf16(w0f[n][1], bfr[rg][1], acc[n][rg], 0, 0, 0);
            }

        // 3+4: per rg: bias+relu -> bf16 Hs-half (4KB, aliases buf) -> A2 frags
        short8 a2[2][4];
#pragma unroll
        for (int rg = 0; rg < 2; ++rg) {
#pragma unroll
            for (int n = 0; n < 8; ++n) {
                const int c0 = n * 16 + g * 4;
                const int u = (2 * n + (g >> 1)) ^ rx;
                unsigned p01 = pack2(fmaxf(acc[n][rg][0] + sB0[c0],     0.f),
                                     fmaxf(acc[n][rg][1] + sB0[c0 + 1], 0.f));
                unsigned p23 = pack2(fmaxf(acc[n][rg][2] + sB0[c0 + 2], 0.f),
                                     fmaxf(acc[n][rg][3] + sB0[c0 + 3], 0.f));
                *(uint2*)(buf + (l15 * 16 + u) * 8 + (g & 1) * 4) = make_uint2(p01, p23);
            }
#pragma unroll
            for (int kk = 0; kk < 4; ++kk)
                a2[rg][kk] = *(const short8*)(buf + (l15 * 16 + ((kk * 4 + g) ^ rx)) * 8);
        }

        // 5: write next tile's feats into buf (all Hs reads done)
        if (tau + 1 < TILES) {
            unsigned pk[16];
#pragma unroll
            for (int i = 0; i < 16; ++i) pk[i] = pack2(pf[i].x, pf[i].y);
            unsigned short* d = buf + sr * 72 + sc * 32;
#pragma unroll
            for (int i = 0; i < 4; ++i)
                ((uint4*)d)[i] = make_uint4(pk[4*i], pk[4*i+1], pk[4*i+2], pk[4*i+3]);
            if (sc == 1) sMeta[w][(tau + 1) & 1][sr] = pmc;
        }

        // 6: GEMM2 + fused epilogue dot (B-frag shared across both rg)
        float rq[2][4] = {{0.f,0.f,0.f,0.f},{0.f,0.f,0.f,0.f}};
#pragma unroll
        for (int n = 0; n < 8; ++n) {
            f32x4 acc2[2] = {(f32x4){0.f,0.f,0.f,0.f}, (f32x4){0.f,0.f,0.f,0.f}};
            const unsigned short* wrow = sWs1 + (n * 16 + l15) * 128;
#pragma unroll
            for (int kk = 0; kk < 4; ++kk) {
                short8 bb = *(const short8*)(wrow + ((kk * 4 + g) ^ rx) * 8);
                acc2[0] = __builtin_amdgcn_mfma_f32_16x16x32_bf16(a2[0][kk], bb, acc2[0], 0, 0, 0);
                acc2[1] = __builtin_amdgcn_mfma_f32_16x16x32_bf16(a2[1][kk], bb, acc2[1], 0, 0, 0);
            }
#pragma unroll
            for (int rg = 0; rg < 2; ++rg)
#pragma unroll
                for (int q = 0; q < 4; ++q)
                    rq[rg][q] += fmaxf(acc2[rg][q] + b1v[n], 0.f) * w2v[n];
        }

        // 7: reduce over l15, store, atomics
#pragma unroll
        for (int off = 1; off < 16; off <<= 1)
#pragma unroll
            for (int rg = 0; rg < 2; ++rg)
#pragma unroll
                for (int q = 0; q < 4; ++q)
                    rq[rg][q] += __shfl_xor(rq[rg][q], off, 64);
        if (l15 == 0) {
#pragma unroll
            for (int rg = 0; rg < 2; ++rg) {
                const size_t m0 = rowb + rg * 16 + g * 4;
                float4 rv = make_float4(rq[rg][0] + b2v, rq[rg][1] + b2v,
                                        rq[rg][2] + b2v, rq[rg][3] + b2v);
                *(float4*)(rawOut + m0) = rv;
                unsigned mcs[4];
#pragma unroll
                for (int j = 0; j < 4; ++j) mcs[j] = sMeta[w][tau & 1][rg * 16 + g * 4 + j];
                *(uint4*)(mcodeOut + m0) = make_uint4(mcs[0], mcs[1], mcs[2], mcs[3]);
                const int bidx = (int)(m0 >> 12);
                const float rvs[4] = {rv.x, rv.y, rv.z, rv.w};
#pragma unroll
                for (int j = 0; j < 4; ++j) {
                    if ((mcs[j] & 1u) && (mcs[j] >> 1)) {
                        int seg = bidx * NG + (int)(mcs[j] >> 1) - 1;
                        atomicAdd(&segCnt[seg], 1u);
                        atomicAdd(&segSum[seg], rvs[j]);
                        atomicMax(&segMax[seg], encf(rvs[j]));
                    }
                }
            }
        }
    }
}

// ---- kernel 2: per-segment stats + bias MLP --------------------------------
__global__ void k_seg(const unsigned* __restrict__ cnt, const float* __restrict__ sum,
                      const unsigned* __restrict__ mx,
                      const float* __restrict__ Wb0, const float* __restrict__ bb0,
                      const float* __restrict__ Wb1, const float* __restrict__ bb1,
                      float4* __restrict__ segstats) {
    int s = blockIdx.x * 256 + threadIdx.x;
    if (s >= NSEG) return;
    unsigned c = cnt[s];
    float smax = (c > 0) ? decf(mx[s]) : 0.f;
    float mean = sum[s] / fmaxf((float)c, 1.f);
    float multi = (c > 1) ? 1.f : 0.f;
    float bias = 0.f;
    if (c > 1) {
        float s0 = smax, s1 = mean, s2 = (float)c;
        bias = bb1[0];
#pragma unroll
        for (int j = 0; j < 32; ++j) {
            float h = s0 * Wb0[j] + s1 * Wb0[32 + j] + s2 * Wb0[64 + j] + bb0[j];
            bias += fmaxf(h, 0.f) * Wb1[j];
        }
    }
    segstats[s] = make_float4(smax, mean, bias, multi);
}

// ---- kernel 3: gather + fair/mask writeout (4 elems/thread) -----------------
__global__ void k_final(const float4* __restrict__ raw4, const uint4* __restrict__ mc4,
                        const float4* __restrict__ segstats, float* __restrict__ out) {
    int i = blockIdx.x * 256 + threadIdx.x;         // group of 4 elems
    float4 rv = raw4[i];
    uint4 mc = mc4[i];
    const float r[4]    = {rv.x, rv.y, rv.z, rv.w};
    const unsigned m[4] = {mc.x, mc.y, mc.z, mc.w};
    const size_t m0 = (size_t)i * 4;
    const int bidx = (int)(m0 >> 12);
    float fair[4], msk[4];
#pragma unroll
    for (int j = 0; j < 4; ++j) {
        msk[j] = (m[j] & 1u) ? 1.0f : 0.0f;
        float f;
        if (m[j] & 1u) {
            f = r[j];
            if (m[j] >> 1) {
                float4 st = segstats[bidx * NG + (int)(m[j] >> 1) - 1];
                if (st.w > 0.5f) f = 1.5f * r[j] - st.y + 0.5f * st.x + st.z;
            }
        } else {
            f = NEGV;
        }
        fair[j] = f;
    }
    *(float4*)(out + m0) = make_float4(fair[0], fair[1], fair[2], fair[3]);
    *(float4*)(out + NELEM + m0) = make_float4(msk[0], msk[1], msk[2], msk[3]);
}

// ---- launch ----------------------------------------------------------------
extern "C" void kernel_launch(void* const* d_in, const int* in_sizes, int n_in,
                              void* d_out, int out_size, void* d_ws, size_t ws_size,
                              hipStream_t stream) {
    const float* X   = (const float*)d_in[0];
    const float* W0  = (const float*)d_in[1];
    const float* b0  = (const float*)d_in[2];
    const float* W1  = (const float*)d_in[3];
    const float* b1  = (const float*)d_in[4];
    const float* W2  = (const float*)d_in[5];
    const float* b2  = (const float*)d_in[6];
    const float* Wb0 = (const float*)d_in[7];
    const float* bb0 = (const float*)d_in[8];
    const float* Wb1 = (const float*)d_in[9];
    const float* bb1 = (const float*)d_in[10];

    char* ws = (char*)d_ws;
    float*          raw      = (float*)(ws + 0);                 // 4 MB
    unsigned*       mcode    = (unsigned*)(ws + 4194304);        // 4 MB
    float4*         segstats = (float4*)(ws + 8388608);          // 2 MB
    unsigned*       cnt      = (unsigned*)(ws + 10485776);
    float*          sum      = (float*)(ws + 11010068);
    unsigned*       mx       = (unsigned*)(ws + 11534360);
    unsigned short* W0T      = (unsigned short*)(ws + 12058656); // 16 KB
    unsigned short* W1Ts     = (unsigned short*)(ws + 12075040); // 32 KB

    hipMemsetAsync(ws + 10485776, 0, 3u * 524292u, stream);      // cnt+sum+mx
    k_prep<<<96, 256, 0, stream>>>(W0, W1, W0T, W1Ts);
    k_mlp<<<GRID_MLP, 256, 0, stream>>>(X, W0T, W1Ts, b0, b1, W2, b2,
                                        raw, mcode, cnt, sum, mx);
    k_seg<<<(NSEG + 255) / 256, 256, 0, stream>>>(cnt, sum, mx, Wb0, bb0, Wb1, bb1, segstats);
    k_final<<<NELEM / 1024, 256, 0, stream>>>((const float4*)raw, (const uint4*)mcode,
                                              segstats, (float*)d_out);
}

// Round 5
// 300.260 us; speedup vs baseline: 1.6738x; 1.6738x over previous
//
#include <hip/hip_runtime.h>
#include <hip/hip_bf16.h>

// Problem constants
#define NB   256
#define NC   4096
#define NF   64
#define NG   512
#define NH   128
#define NELEM (NB*NC)            // 1048576
#define NSEG  (NB*NG + 1)        // 131073
#define LDX  66                  // row stride of x_with_meta in floats
#define NEGV (-1000000000.0f)
#define TILES 4                  // 128-row tiles per block
#define TILE_ROWS 128
#define GRID_MLP (NELEM/(TILES*TILE_ROWS))   // 2048

typedef __attribute__((ext_vector_type(8))) short short8;
typedef __attribute__((ext_vector_type(4))) float f32x4;

// truncating f32->bf16 pair pack (threshold 2e7 makes RNE unnecessary)
__device__ __forceinline__ unsigned pack2(float x, float y) {
    return (__float_as_uint(y) & 0xFFFF0000u) | (__float_as_uint(x) >> 16);
}
__device__ __forceinline__ unsigned short f2bf(float f) {   // RNE, off hot path
    unsigned u = __float_as_uint(f);
    return (unsigned short)((u + 0x7FFFu + ((u >> 16) & 1u)) >> 16);
}
__device__ __forceinline__ unsigned encf(float f) {
    unsigned u = __float_as_uint(f);
    return (u & 0x80000000u) ? ~u : (u | 0x80000000u);
}
__device__ __forceinline__ float decf(unsigned u) {
    unsigned v = (u & 0x80000000u) ? (u ^ 0x80000000u) : ~u;
    return __uint_as_float(v);
}

// ---- kernel 0: weight prep (RNE, off hot path) ------------------------------
// W0T: [h=128][f=64] bf16 linear (A-frag source for swapped GEMM1)
// W1Ts: [j=128][16 units of 8 bf16], unit index XOR-swizzled: u' = u ^ (j&7)
__global__ void k_prep(const float* __restrict__ W0, const float* __restrict__ W1,
                       unsigned short* __restrict__ W0T, unsigned short* __restrict__ W1Ts) {
    int i = blockIdx.x * 256 + threadIdx.x;
    if (i < 8192) {                       // W0T[j][k] = W0[k][j]
        int j = i >> 6, k = i & 63;
        W0T[i] = f2bf(W0[k * NH + j]);
    } else if (i < 8192 + 16384) {        // W1Ts swizzled: elem (j, c)
        int i2 = i - 8192;
        int j = i2 >> 7, c = i2 & 127;
        int u = c >> 3, d = c & 7;
        W1Ts[(j * 16 + (u ^ (j & 7))) * 8 + d] = f2bf(W1[c * NH + j]);
    }
}

// ---- kernel 1: fused MLP + segment atomics ---------------------------------
// 4 waves x 32 rows = 128-row tiles, TILES per block, barrier-free main loop.
// LDS 52.7KB -> 3 blocks/CU by LDS; VGPR cap 128 (launch_bounds(256,2)) -> no spill.
__global__ __launch_bounds__(256, 2) void k_mlp(
        const float* __restrict__ X,
        const unsigned short* __restrict__ W0T,
        const unsigned short* __restrict__ W1Ts,
        const float* __restrict__ b0, const float* __restrict__ b1,
        const float* __restrict__ W2, const float* __restrict__ b2p,
        float* __restrict__ rawOut, unsigned* __restrict__ mcodeOut,
        unsigned* __restrict__ segCnt, float* __restrict__ segSum,
        unsigned* __restrict__ segMax) {
    __shared__ __align__(16) unsigned short sWs1[16384];     // 32 KB W1 frags (swizzled)
    __shared__ __align__(16) unsigned short sBuf[4][2304];   // 4.5 KB/wave: feats/Hs aliased
    __shared__ float sB0[128];
    __shared__ unsigned sMeta[4][2][32];                     // per-wave meta codes, dbuf

    const int t = threadIdx.x, w = t >> 6, l = t & 63;
    const int l15 = l & 15, g = l >> 4;
    const int rx = l15 & 7;

    // stage W1 (pre-swizzled, linear copy; once per block)
    {
        const uint4* src = (const uint4*)W1Ts;
        uint4* dst = (uint4*)sWs1;
#pragma unroll
        for (int i = 0; i < 8; ++i) dst[i * 256 + t] = src[i * 256 + t];
    }
    if (t < 128) sB0[t] = b0[t];

    // loop-invariant register fragments
    short8 w0f[8][2];
#pragma unroll
    for (int n = 0; n < 8; ++n)
#pragma unroll
        for (int kk = 0; kk < 2; ++kk)
            w0f[n][kk] = *(const short8*)(W0T + (n * 16 + l15) * 64 + kk * 32 + g * 8);
    float b1v[8], w2v[8];
#pragma unroll
    for (int n = 0; n < 8; ++n) { b1v[n] = b1[n * 16 + l15]; w2v[n] = W2[n * 16 + l15]; }
    const float b2v = b2p[0];

    __syncthreads();   // only barrier: sWs1/sB0 ready

    unsigned short* buf = sBuf[w];
    const size_t rowwave0 = (size_t)blockIdx.x * (TILES * TILE_ROWS) + w * 32;
    const int sr = l >> 1, sc = l & 1;   // staging role: row sr, col-half sc

    // ---- prologue: stage tile 0 ----
    float2 pf[16];
    unsigned pmc = 0;
    {
        const float* src = X + (rowwave0 + sr) * LDX + sc * 32;
#pragma unroll
        for (int i = 0; i < 16; ++i) pf[i] = *(const float2*)(src + 2 * i);
        if (sc == 1) {
            float2 mt = *(const float2*)(X + (rowwave0 + sr) * LDX + 64);
            pmc = ((unsigned)((int)mt.x + 1) << 1) | (mt.y > 0.f ? 1u : 0u);
        }
    }
    {
        unsigned pk[16];
#pragma unroll
        for (int i = 0; i < 16; ++i) pk[i] = pack2(pf[i].x, pf[i].y);
        unsigned short* d = buf + sr * 72 + sc * 32;
#pragma unroll
        for (int i = 0; i < 4; ++i)
            ((uint4*)d)[i] = make_uint4(pk[4*i], pk[4*i+1], pk[4*i+2], pk[4*i+3]);
        if (sc == 1) sMeta[w][0][sr] = pmc;
    }

    for (int tau = 0; tau < TILES; ++tau) {
        const size_t rowb = rowwave0 + (size_t)tau * TILE_ROWS;

        // 0: issue next tile's global loads (in flight across the iteration)
        if (tau + 1 < TILES) {
            const float* src = X + (rowb + TILE_ROWS + sr) * LDX + sc * 32;
#pragma unroll
            for (int i = 0; i < 16; ++i) pf[i] = *(const float2*)(src + 2 * i);
            if (sc == 1) {
                float2 mt = *(const float2*)(X + (rowb + TILE_ROWS + sr) * LDX + 64);
                pmc = ((unsigned)((int)mt.x + 1) << 1) | (mt.y > 0.f ? 1u : 0u);
            }
        }

        // 1: feats fragments (row rg*16+l15, cols kk*32+g*8..+7)
        short8 bfr[2][2];
#pragma unroll
        for (int rg = 0; rg < 2; ++rg)
#pragma unroll
            for (int kk = 0; kk < 2; ++kk)
                bfr[rg][kk] = *(const short8*)(buf + (rg * 16 + l15) * 72 + kk * 32 + g * 8);

        // 2: GEMM1 (swapped): lane holds h1[row l15][col n*16+g*4+q] per rg
        f32x4 acc[8][2];
#pragma unroll
        for (int n = 0; n < 8; ++n)
#pragma unroll
            for (int rg = 0; rg < 2; ++rg) acc[n][rg] = (f32x4){0.f, 0.f, 0.f, 0.f};
#pragma unroll
        for (int n = 0; n < 8; ++n)
#pragma unroll
            for (int rg = 0; rg < 2; ++rg) {
                acc[n][rg] = __builtin_amdgcn_mfma_f32_16x16x32_bf16(w0f[n][0], bfr[rg][0], acc[n][rg], 0, 0, 0);
                acc[n][rg] = __builtin_amdgcn_mfma_f32_16x16x32_bf16(w0f[n][1], bfr[rg][1], acc[n][rg], 0, 0, 0);
            }

        // 3+4: per rg: bias+relu -> bf16 Hs-half (4KB, aliases buf) -> A2 frags
        short8 a2[2][4];
#pragma unroll
        for (int rg = 0; rg < 2; ++rg) {
#pragma unroll
            for (int n = 0; n < 8; ++n) {
                const int c0 = n * 16 + g * 4;
                const int u = (2 * n + (g >> 1)) ^ rx;
                unsigned p01 = pack2(fmaxf(acc[n][rg][0] + sB0[c0],     0.f),
                                     fmaxf(acc[n][rg][1] + sB0[c0 + 1], 0.f));
                unsigned p23 = pack2(fmaxf(acc[n][rg][2] + sB0[c0 + 2], 0.f),
                                     fmaxf(acc[n][rg][3] + sB0[c0 + 3], 0.f));
                *(uint2*)(buf + (l15 * 16 + u) * 8 + (g & 1) * 4) = make_uint2(p01, p23);
            }
#pragma unroll
            for (int kk = 0; kk < 4; ++kk)
                a2[rg][kk] = *(const short8*)(buf + (l15 * 16 + ((kk * 4 + g) ^ rx)) * 8);
        }

        // 5: write next tile's feats into buf (all Hs reads done)
        if (tau + 1 < TILES) {
            unsigned pk[16];
#pragma unroll
            for (int i = 0; i < 16; ++i) pk[i] = pack2(pf[i].x, pf[i].y);
            unsigned short* d = buf + sr * 72 + sc * 32;
#pragma unroll
            for (int i = 0; i < 4; ++i)
                ((uint4*)d)[i] = make_uint4(pk[4*i], pk[4*i+1], pk[4*i+2], pk[4*i+3]);
            if (sc == 1) sMeta[w][(tau + 1) & 1][sr] = pmc;
        }

        // 6: GEMM2 + fused epilogue dot (B-frag shared across both rg)
        float rq[2][4] = {{0.f,0.f,0.f,0.f},{0.f,0.f,0.f,0.f}};
#pragma unroll
        for (int n = 0; n < 8; ++n) {
            f32x4 acc2[2] = {(f32x4){0.f,0.f,0.f,0.f}, (f32x4){0.f,0.f,0.f,0.f}};
            const unsigned short* wrow = sWs1 + (n * 16 + l15) * 128;
#pragma unroll
            for (int kk = 0; kk < 4; ++kk) {
                short8 bb = *(const short8*)(wrow + ((kk * 4 + g) ^ rx) * 8);
                acc2[0] = __builtin_amdgcn_mfma_f32_16x16x32_bf16(a2[0][kk], bb, acc2[0], 0, 0, 0);
                acc2[1] = __builtin_amdgcn_mfma_f32_16x16x32_bf16(a2[1][kk], bb, acc2[1], 0, 0, 0);
            }
#pragma unroll
            for (int rg = 0; rg < 2; ++rg)
#pragma unroll
                for (int q = 0; q < 4; ++q)
                    rq[rg][q] += fmaxf(acc2[rg][q] + b1v[n], 0.f) * w2v[n];
        }

        // 7: reduce over l15, store, atomics
#pragma unroll
        for (int off = 1; off < 16; off <<= 1)
#pragma unroll
            for (int rg = 0; rg < 2; ++rg)
#pragma unroll
                for (int q = 0; q < 4; ++q)
                    rq[rg][q] += __shfl_xor(rq[rg][q], off, 64);
        if (l15 == 0) {
#pragma unroll
            for (int rg = 0; rg < 2; ++rg) {
                const size_t m0 = rowb + rg * 16 + g * 4;
                float4 rv = make_float4(rq[rg][0] + b2v, rq[rg][1] + b2v,
                                        rq[rg][2] + b2v, rq[rg][3] + b2v);
                *(float4*)(rawOut + m0) = rv;
                unsigned mcs[4];
#pragma unroll
                for (int j = 0; j < 4; ++j) mcs[j] = sMeta[w][tau & 1][rg * 16 + g * 4 + j];
                *(uint4*)(mcodeOut + m0) = make_uint4(mcs[0], mcs[1], mcs[2], mcs[3]);
                const int bidx = (int)(m0 >> 12);
                const float rvs[4] = {rv.x, rv.y, rv.z, rv.w};
#pragma unroll
                for (int j = 0; j < 4; ++j) {
                    if ((mcs[j] & 1u) && (mcs[j] >> 1)) {
                        int seg = bidx * NG + (int)(mcs[j] >> 1) - 1;
                        atomicAdd(&segCnt[seg], 1u);
                        atomicAdd(&segSum[seg], rvs[j]);
                        atomicMax(&segMax[seg], encf(rvs[j]));
                    }
                }
            }
        }
    }
}

// ---- kernel 2: per-segment stats + bias MLP --------------------------------
__global__ void k_seg(const unsigned* __restrict__ cnt, const float* __restrict__ sum,
                      const unsigned* __restrict__ mx,
                      const float* __restrict__ Wb0, const float* __restrict__ bb0,
                      const float* __restrict__ Wb1, const float* __restrict__ bb1,
                      float4* __restrict__ segstats) {
    int s = blockIdx.x * 256 + threadIdx.x;
    if (s >= NSEG) return;
    unsigned c = cnt[s];
    float smax = (c > 0) ? decf(mx[s]) : 0.f;
    float mean = sum[s] / fmaxf((float)c, 1.f);
    float multi = (c > 1) ? 1.f : 0.f;
    float bias = 0.f;
    if (c > 1) {
        float s0 = smax, s1 = mean, s2 = (float)c;
        bias = bb1[0];
#pragma unroll
        for (int j = 0; j < 32; ++j) {
            float h = s0 * Wb0[j] + s1 * Wb0[32 + j] + s2 * Wb0[64 + j] + bb0[j];
            bias += fmaxf(h, 0.f) * Wb1[j];
        }
    }
    segstats[s] = make_float4(smax, mean, bias, multi);
}

// ---- kernel 3: gather + fair/mask writeout (4 elems/thread) -----------------
__global__ void k_final(const float4* __restrict__ raw4, const uint4* __restrict__ mc4,
                        const float4* __restrict__ segstats, float* __restrict__ out) {
    int i = blockIdx.x * 256 + threadIdx.x;         // group of 4 elems
    float4 rv = raw4[i];
    uint4 mc = mc4[i];
    const float r[4]    = {rv.x, rv.y, rv.z, rv.w};
    const unsigned m[4] = {mc.x, mc.y, mc.z, mc.w};
    const size_t m0 = (size_t)i * 4;
    const int bidx = (int)(m0 >> 12);
    float fair[4], msk[4];
#pragma unroll
    for (int j = 0; j < 4; ++j) {
        msk[j] = (m[j] & 1u) ? 1.0f : 0.0f;
        float f;
        if (m[j] & 1u) {
            f = r[j];
            if (m[j] >> 1) {
                float4 st = segstats[bidx * NG + (int)(m[j] >> 1) - 1];
                if (st.w > 0.5f) f = 1.5f * r[j] - st.y + 0.5f * st.x + st.z;
            }
        } else {
            f = NEGV;
        }
        fair[j] = f;
    }
    *(float4*)(out + m0) = make_float4(fair[0], fair[1], fair[2], fair[3]);
    *(float4*)(out + NELEM + m0) = make_float4(msk[0], msk[1], msk[2], msk[3]);
}

// ---- launch ----------------------------------------------------------------
extern "C" void kernel_launch(void* const* d_in, const int* in_sizes, int n_in,
                              void* d_out, int out_size, void* d_ws, size_t ws_size,
                              hipStream_t stream) {
    const float* X   = (const float*)d_in[0];
    const float* W0  = (const float*)d_in[1];
    const float* b0  = (const float*)d_in[2];
    const float* W1  = (const float*)d_in[3];
    const float* b1  = (const float*)d_in[4];
    const float* W2  = (const float*)d_in[5];
    const float* b2  = (const float*)d_in[6];
    const float* Wb0 = (const float*)d_in[7];
    const float* bb0 = (const float*)d_in[8];
    const float* Wb1 = (const float*)d_in[9];
    const float* bb1 = (const float*)d_in[10];

    char* ws = (char*)d_ws;
    float*          raw      = (float*)(ws + 0);                 // 4 MB
    unsigned*       mcode    = (unsigned*)(ws + 4194304);        // 4 MB
    float4*         segstats = (float4*)(ws + 8388608);          // 2 MB
    unsigned*       cnt      = (unsigned*)(ws + 10485776);
    float*          sum      = (float*)(ws + 11010068);
    unsigned*       mx       = (unsigned*)(ws + 11534360);
    unsigned short* W0T      = (unsigned short*)(ws + 12058656); // 16 KB
    unsigned short* W1Ts     = (unsigned short*)(ws + 12075040); // 32 KB

    hipMemsetAsync(ws + 10485776, 0, 3u * 524292u, stream);      // cnt+sum+mx
    k_prep<<<96, 256, 0, stream>>>(W0, W1, W0T, W1Ts);
    k_mlp<<<GRID_MLP, 256, 0, stream>>>(X, W0T, W1Ts, b0, b1, W2, b2,
                                        raw, mcode, cnt, sum, mx);
    k_seg<<<(NSEG + 255) / 256, 256, 0, stream>>>(cnt, sum, mx, Wb0, bb0, Wb1, bb1, segstats);
    k_final<<<NELEM / 1024, 256, 0, stream>>>((const float4*)raw, (const uint4*)mcode,
                                              segstats, (float*)d_out);
}

// Round 6
// 243.964 us; speedup vs baseline: 2.0601x; 1.2308x over previous
//
#include <hip/hip_runtime.h>
#include <hip/hip_bf16.h>

// Problem constants
#define NB   256
#define NC   4096
#define NF   64
#define NG   512
#define NH   128
#define NELEM (NB*NC)            // 1048576
#define NSEG  (NB*NG + 1)        // 131073
#define LDX  66                  // row stride of x_with_meta in floats
#define NEGV (-1000000000.0f)
#define TILES 8                  // 128-row tiles per block
#define TILE_ROWS 128
#define GRID_MLP (NELEM/(TILES*TILE_ROWS))   // 1024

typedef __attribute__((ext_vector_type(8))) short short8;
typedef __attribute__((ext_vector_type(4))) float f32x4;

// truncating f32->bf16 pair pack (threshold makes RNE unnecessary on hot path)
__device__ __forceinline__ unsigned pack2(float x, float y) {
    return (__float_as_uint(y) & 0xFFFF0000u) | (__float_as_uint(x) >> 16);
}
__device__ __forceinline__ unsigned short f2bf(float f) {   // RNE, off hot path
    unsigned u = __float_as_uint(f);
    return (unsigned short)((u + 0x7FFFu + ((u >> 16) & 1u)) >> 16);
}
__device__ __forceinline__ unsigned char f2fp8(float f) {   // e4m3, off hot path
    return (unsigned char)((unsigned)__builtin_amdgcn_cvt_pk_fp8_f32(f, 0.f, 0, false) & 0xFFu);
}
__device__ __forceinline__ unsigned encf(float f) {
    unsigned u = __float_as_uint(f);
    return (u & 0x80000000u) ? ~u : (u | 0x80000000u);
}
__device__ __forceinline__ float decf(unsigned u) {
    unsigned v = (u & 0x80000000u) ? (u ^ 0x80000000u) : ~u;
    return __uint_as_float(v);
}
__device__ __forceinline__ f32x4 mfma_fp8(long a, long b, f32x4 c) {
    return __builtin_amdgcn_mfma_f32_16x16x32_fp8_fp8(a, b, c, 0, 0, 0);
}

// ---- kernel 0: weight prep --------------------------------------------------
// W0T: [h=128][f=64] bf16 linear (A-frag source for swapped GEMM1)
// W1f8s: [j=128][16 units of 8 fp8], unit index XOR-swizzled: u' = u ^ (j&7)
__global__ void k_prep(const float* __restrict__ W0, const float* __restrict__ W1,
                       unsigned short* __restrict__ W0T, unsigned char* __restrict__ W1f8s) {
    int i = blockIdx.x * 256 + threadIdx.x;
    if (i < 8192) {                       // W0T[j][k] = W0[k][j]
        int j = i >> 6, k = i & 63;
        W0T[i] = f2bf(W0[k * NH + j]);
    } else if (i < 8192 + 16384) {        // W1f8s swizzled: elem (j, c)
        int i2 = i - 8192;
        int j = i2 >> 7, c = i2 & 127;
        W1f8s[(j * 16 + ((c >> 3) ^ (j & 7))) * 8 + (c & 7)] = f2fp8(W1[c * NH + j]);
    }
}

// ---- kernel 1: fused MLP + segment atomics ---------------------------------
// 4 waves x 32 rows = 128-row tiles, TILES per block, barrier-free main loop.
// LDS 37.4 KB -> 4 blocks/CU (16 waves). Dataflow identical to round-3 skeleton.
__global__ __launch_bounds__(256, 2) void k_mlp(
        const float* __restrict__ X,
        const unsigned short* __restrict__ W0T,
        const unsigned char* __restrict__ W1f8s,
        const float* __restrict__ b0, const float* __restrict__ b1,
        const float* __restrict__ W2, const float* __restrict__ b2p,
        float* __restrict__ rawOut, float2* __restrict__ meta2,
        unsigned* __restrict__ segCnt, float* __restrict__ segSum,
        unsigned* __restrict__ segMax) {
    __shared__ __align__(16) unsigned char sW1f[16384];      // 16 KB W1 fp8 frags (swizzled)
    __shared__ __align__(16) unsigned short sBuf[4][2304];   // 4.5 KB/wave: feats bf16 / Hs fp8 aliased
    __shared__ float sB0[128];
    __shared__ float2 sMeta[4][2][32];                       // per-wave meta, double-buffered

    const int t = threadIdx.x, w = t >> 6, l = t & 63;
    const int l15 = l & 15, g = l >> 4;
    const int rx = l15 & 7;

    // stage W1 fp8 (pre-swizzled, linear copy; once per block)
    {
        const uint4* src = (const uint4*)W1f8s;
        uint4* dst = (uint4*)sW1f;
#pragma unroll
        for (int i = 0; i < 4; ++i) dst[i * 256 + t] = src[i * 256 + t];
    }
    if (t < 128) sB0[t] = b0[t];

    // loop-invariant register fragments
    short8 w0f[8][2];
#pragma unroll
    for (int n = 0; n < 8; ++n)
#pragma unroll
        for (int kk = 0; kk < 2; ++kk)
            w0f[n][kk] = *(const short8*)(W0T + (n * 16 + l15) * 64 + kk * 32 + g * 8);
    float b1v[8], w2v[8];
#pragma unroll
    for (int n = 0; n < 8; ++n) { b1v[n] = b1[n * 16 + l15]; w2v[n] = W2[n * 16 + l15]; }
    const float b2v = b2p[0];

    __syncthreads();   // only barrier: sW1f/sB0 ready

    unsigned short* buf = sBuf[w];
    unsigned char* hsb = (unsigned char*)buf;    // Hs fp8 view (4 KB, aliases feats)
    const size_t rowwave0 = (size_t)blockIdx.x * (TILES * TILE_ROWS) + w * 32;
    const int sr = l >> 1, sc = l & 1;   // staging role: row sr, col-half sc

    // ---- prologue: stage tile 0 (coalesced f32 -> bf16 -> own-wave LDS) ----
    float2 pf[16];
    float2 mt;
    {
        const float* src = X + (rowwave0 + sr) * LDX + sc * 32;
#pragma unroll
        for (int i = 0; i < 16; ++i) pf[i] = *(const float2*)(src + 2 * i);
        if (sc == 1) mt = *(const float2*)(X + (rowwave0 + sr) * LDX + 64);
    }
    {
        unsigned pk[16];
#pragma unroll
        for (int i = 0; i < 16; ++i) pk[i] = pack2(pf[i].x, pf[i].y);
        unsigned short* d = buf + sr * 72 + sc * 32;
#pragma unroll
        for (int i = 0; i < 4; ++i)
            ((uint4*)d)[i] = make_uint4(pk[4*i], pk[4*i+1], pk[4*i+2], pk[4*i+3]);
        if (sc == 1) sMeta[w][0][sr] = mt;
    }

    for (int tau = 0; tau < TILES; ++tau) {
        const size_t rowb = rowwave0 + (size_t)tau * TILE_ROWS;

        // 0: issue next tile's global loads (in flight across whole iteration)
        if (tau + 1 < TILES) {
            const float* src = X + (rowb + TILE_ROWS + sr) * LDX + sc * 32;
#pragma unroll
            for (int i = 0; i < 16; ++i) pf[i] = *(const float2*)(src + 2 * i);
            if (sc == 1) mt = *(const float2*)(X + (rowb + TILE_ROWS + sr) * LDX + 64);
        }

        // 1: feats fragments (row rg*16+l15, cols kk*32+g*8..+7)
        short8 bfr[2][2];
#pragma unroll
        for (int rg = 0; rg < 2; ++rg)
#pragma unroll
            for (int kk = 0; kk < 2; ++kk)
                bfr[rg][kk] = *(const short8*)(buf + (rg * 16 + l15) * 72 + kk * 32 + g * 8);

        // 2: GEMM1 (swapped, bf16): lane holds h1[row l15][col n*16+g*4+q] per rg
        f32x4 acc[8][2];
#pragma unroll
        for (int n = 0; n < 8; ++n)
#pragma unroll
            for (int rg = 0; rg < 2; ++rg) acc[n][rg] = (f32x4){0.f, 0.f, 0.f, 0.f};
#pragma unroll
        for (int n = 0; n < 8; ++n)
#pragma unroll
            for (int rg = 0; rg < 2; ++rg) {
                acc[n][rg] = __builtin_amdgcn_mfma_f32_16x16x32_bf16(w0f[n][0], bfr[rg][0], acc[n][rg], 0, 0, 0);
                acc[n][rg] = __builtin_amdgcn_mfma_f32_16x16x32_bf16(w0f[n][1], bfr[rg][1], acc[n][rg], 0, 0, 0);
            }

        // 3: bias+relu -> fp8 Hs (XOR-swizzled 8B units), both rg (round-3 order)
#pragma unroll
        for (int n = 0; n < 8; ++n) {
            const int c0 = n * 16 + g * 4;
            const float bv0 = sB0[c0], bv1 = sB0[c0+1], bv2 = sB0[c0+2], bv3 = sB0[c0+3];
            const int u = (2 * n + (g >> 1)) ^ rx;
#pragma unroll
            for (int rg = 0; rg < 2; ++rg) {
                unsigned d = (unsigned)__builtin_amdgcn_cvt_pk_fp8_f32(
                    fmaxf(acc[n][rg][0] + bv0, 0.f), fmaxf(acc[n][rg][1] + bv1, 0.f), 0, false);
                d = (unsigned)__builtin_amdgcn_cvt_pk_fp8_f32(
                    fmaxf(acc[n][rg][2] + bv2, 0.f), fmaxf(acc[n][rg][3] + bv3, 0.f), (int)d, true);
                *(unsigned*)(hsb + ((rg * 16 + l15) * 16 + u) * 8 + (g & 1) * 4) = d;
            }
        }

        // 4: A2 fragments (fp8, row rg*16+l15, K elems kk*32+g*8..+7, swizzled)
        long a2[2][4];
#pragma unroll
        for (int rg = 0; rg < 2; ++rg)
#pragma unroll
            for (int kk = 0; kk < 4; ++kk)
                a2[rg][kk] = *(const long*)(hsb + ((rg * 16 + l15) * 16 + ((kk * 4 + g) ^ rx)) * 8);

        // 5: write next tile's feats into buf (all Hs reads done)
        if (tau + 1 < TILES) {
            unsigned pk[16];
#pragma unroll
            for (int i = 0; i < 16; ++i) pk[i] = pack2(pf[i].x, pf[i].y);
            unsigned short* d = buf + sr * 72 + sc * 32;
#pragma unroll
            for (int i = 0; i < 4; ++i)
                ((uint4*)d)[i] = make_uint4(pk[4*i], pk[4*i+1], pk[4*i+2], pk[4*i+3]);
            if (sc == 1) sMeta[w][(tau + 1) & 1][sr] = mt;
        }

        // 6: GEMM2 (fp8) + fused epilogue dot (B-frag shared across both rg)
        float rq[2][4] = {{0.f,0.f,0.f,0.f},{0.f,0.f,0.f,0.f}};
#pragma unroll
        for (int n = 0; n < 8; ++n) {
            f32x4 acc2[2] = {(f32x4){0.f,0.f,0.f,0.f}, (f32x4){0.f,0.f,0.f,0.f}};
            const unsigned char* wrow = sW1f + (n * 16 + l15) * 128;
#pragma unroll
            for (int kk = 0; kk < 4; ++kk) {
                long bb = *(const long*)(wrow + ((kk * 4 + g) ^ rx) * 8);
                acc2[0] = mfma_fp8(a2[0][kk], bb, acc2[0]);
                acc2[1] = mfma_fp8(a2[1][kk], bb, acc2[1]);
            }
#pragma unroll
            for (int rg = 0; rg < 2; ++rg)
#pragma unroll
                for (int q = 0; q < 4; ++q)
                    rq[rg][q] += fmaxf(acc2[rg][q] + b1v[n], 0.f) * w2v[n];
        }

        // 7: reduce over l15 (h2 cols), store, atomics
#pragma unroll
        for (int off = 1; off < 16; off <<= 1)
#pragma unroll
            for (int rg = 0; rg < 2; ++rg)
#pragma unroll
                for (int q = 0; q < 4; ++q)
                    rq[rg][q] += __shfl_xor(rq[rg][q], off, 64);
        if (l15 == 0) {
#pragma unroll
            for (int rg = 0; rg < 2; ++rg) {
                const size_t m0 = rowb + rg * 16 + g * 4;
                float4 rv = make_float4(rq[rg][0] + b2v, rq[rg][1] + b2v,
                                        rq[rg][2] + b2v, rq[rg][3] + b2v);
                *(float4*)(rawOut + m0) = rv;
                float2 mts[4];
#pragma unroll
                for (int j = 0; j < 4; ++j) mts[j] = sMeta[w][tau & 1][rg * 16 + g * 4 + j];
                ((float4*)(meta2 + m0))[0] = make_float4(mts[0].x, mts[0].y, mts[1].x, mts[1].y);
                ((float4*)(meta2 + m0))[1] = make_float4(mts[2].x, mts[2].y, mts[3].x, mts[3].y);
                const int bidx = (int)(m0 >> 12);
                const float rvs[4] = {rv.x, rv.y, rv.z, rv.w};
#pragma unroll
                for (int j = 0; j < 4; ++j) {
                    int gid = (int)mts[j].x;
                    if (mts[j].y > 0.f && gid >= 0) {
                        int seg = bidx * NG + gid;
                        atomicAdd(&segCnt[seg], 1u);
                        atomicAdd(&segSum[seg], rvs[j]);
                        atomicMax(&segMax[seg], encf(rvs[j]));
                    }
                }
            }
        }
    }
}

// ---- kernel 2: per-segment stats + bias MLP --------------------------------
__global__ void k_seg(const unsigned* __restrict__ cnt, const float* __restrict__ sum,
                      const unsigned* __restrict__ mx,
                      const float* __restrict__ Wb0, const float* __restrict__ bb0,
                      const float* __restrict__ Wb1, const float* __restrict__ bb1,
                      float4* __restrict__ segstats) {
    int s = blockIdx.x * 256 + threadIdx.x;
    if (s >= NSEG) return;
    unsigned c = cnt[s];
    float smax = (c > 0) ? decf(mx[s]) : 0.f;
    float mean = sum[s] / fmaxf((float)c, 1.f);
    float multi = (c > 1) ? 1.f : 0.f;
    float bias = 0.f;
    if (c > 1) {
        float s0 = smax, s1 = mean, s2 = (float)c;
        bias = bb1[0];
#pragma unroll
        for (int j = 0; j < 32; ++j) {
            float h = s0 * Wb0[j] + s1 * Wb0[32 + j] + s2 * Wb0[64 + j] + bb0[j];
            bias += fmaxf(h, 0.f) * Wb1[j];
        }
    }
    segstats[s] = make_float4(smax, mean, bias, multi);
}

// ---- kernel 3: gather + fair/mask writeout (4 elems/thread) -----------------
__global__ void k_final(const float4* __restrict__ raw4, const float4* __restrict__ meta4,
                        const float4* __restrict__ segstats, float* __restrict__ out) {
    int i = blockIdx.x * 256 + threadIdx.x;         // group of 4 elems
    float4 rv = raw4[i];
    float4 mA = meta4[2 * i], mB = meta4[2 * i + 1];
    const float r[4]   = {rv.x, rv.y, rv.z, rv.w};
    const float gidf[4]= {mA.x, mA.z, mB.x, mB.z};
    const float msk[4] = {mA.y, mA.w, mB.y, mB.w};
    const size_t m0 = (size_t)i * 4;
    const int bidx = (int)(m0 >> 12);
    float fair[4];
#pragma unroll
    for (int j = 0; j < 4; ++j) {
        int gid = (int)gidf[j];
        float f;
        if (msk[j] > 0.f) {
            f = r[j];
            if (gid >= 0) {
                float4 st = segstats[bidx * NG + gid];
                if (st.w > 0.5f) f = 1.5f * r[j] - st.y + 0.5f * st.x + st.z;
            }
        } else {
            f = NEGV;
        }
        fair[j] = f;
    }
    *(float4*)(out + m0) = make_float4(fair[0], fair[1], fair[2], fair[3]);
    *(float4*)(out + NELEM + m0) = make_float4(msk[0], msk[1], msk[2], msk[3]);
}

// ---- launch ----------------------------------------------------------------
extern "C" void kernel_launch(void* const* d_in, const int* in_sizes, int n_in,
                              void* d_out, int out_size, void* d_ws, size_t ws_size,
                              hipStream_t stream) {
    const float* X   = (const float*)d_in[0];
    const float* W0  = (const float*)d_in[1];
    const float* b0  = (const float*)d_in[2];
    const float* W1  = (const float*)d_in[3];
    const float* b1  = (const float*)d_in[4];
    const float* W2  = (const float*)d_in[5];
    const float* b2  = (const float*)d_in[6];
    const float* Wb0 = (const float*)d_in[7];
    const float* bb0 = (const float*)d_in[8];
    const float* Wb1 = (const float*)d_in[9];
    const float* bb1 = (const float*)d_in[10];

    char* ws = (char*)d_ws;
    float*          raw      = (float*)(ws + 0);                 //  4 MB
    float2*         meta2    = (float2*)(ws + 4194304);          //  8 MB
    float4*         segstats = (float4*)(ws + 12582912);         //  2 MB
    unsigned*       cnt      = (unsigned*)(ws + 14680080);
    float*          sum      = (float*)(ws + 15204372);
    unsigned*       mx       = (unsigned*)(ws + 15728664);
    unsigned short* W0T      = (unsigned short*)(ws + 16252960); // 16 KB
    unsigned char*  W1f8s    = (unsigned char*)(ws + 16269344);  // 16 KB

    hipMemsetAsync(ws + 14680080, 0, 3u * 524292u, stream);      // cnt+sum+mx
    k_prep<<<96, 256, 0, stream>>>(W0, W1, W0T, W1f8s);
    k_mlp<<<GRID_MLP, 256, 0, stream>>>(X, W0T, W1f8s, b0, b1, W2, b2,
                                        raw, meta2, cnt, sum, mx);
    k_seg<<<(NSEG + 255) / 256, 256, 0, stream>>>(cnt, sum, mx, Wb0, bb0, Wb1, bb1, segstats);
    k_final<<<NELEM / 1024, 256, 0, stream>>>((const float4*)raw, (const float4*)meta2,
                                              segstats, (float*)d_out);
}